// Round 1
// baseline (476.232 us; speedup 1.0000x reference)
//
#include <hip/hip_runtime.h>

// LoRA forward: out = 0.25 * (x @ (A*sA)^T) @ (B*sB)^T
// x: [16384, 4096] f32, A: [64, 4096] f32, B: [4096, 64] f32
// Strategy: dequant A/B to bf16 (fold scales + 0.25 into B), then two
// bf16-MFMA GEMMs. Both GEMMs are HBM-bound (read x / write out); MFMA
// makes compute negligible (fp32 VALU would exceed the memory floor).

#define M_TOTAL 16384
#define DIN     4096
#define DOUT    4096
#define RANK    64

typedef __bf16 bf16_8 __attribute__((ext_vector_type(8)));
typedef __bf16 bf16_4 __attribute__((ext_vector_type(4)));
typedef float  f32x4  __attribute__((ext_vector_type(4)));

// ---------------- prep: dequantize A and B into bf16 ----------------
// 262144 elements each; 4 elements/thread. Scale index is constant across
// a 4-aligned group for both arrays (row lengths 4096 and 64 divisible by 4).
__global__ __launch_bounds__(256) void prep_kernel(
    const float* __restrict__ A, const float* __restrict__ Bm,
    const float* __restrict__ sA, const float* __restrict__ sB,
    __bf16* __restrict__ Abf, __bf16* __restrict__ Bbf) {
  int i = (blockIdx.x * 256 + threadIdx.x) * 4;
  float4 a = *(const float4*)(A + i);
  float sa = sA[i >> 12];                 // A row = i / 4096
  bf16_4 va;
  va[0] = (__bf16)(a.x * sa); va[1] = (__bf16)(a.y * sa);
  va[2] = (__bf16)(a.z * sa); va[3] = (__bf16)(a.w * sa);
  *(bf16_4*)(Abf + i) = va;

  float4 b = *(const float4*)(Bm + i);
  float sb = sB[i >> 6] * 0.25f;          // B row = i / 64; fold SCALING
  bf16_4 vb;
  vb[0] = (__bf16)(b.x * sb); vb[1] = (__bf16)(b.y * sb);
  vb[2] = (__bf16)(b.z * sb); vb[3] = (__bf16)(b.w * sb);
  *(bf16_4*)(Bbf + i) = vb;
}

// ---------------- gemm1: h[M,64] = x[M,K] @ Abf[64,K]^T ----------------
// BM=32 rows/block, BK=64, 256 threads (4 waves). Grid = 512 (2 blocks/CU).
// Wave w: m-tile = w>>1 (16 rows), n-half = w&1 (32 of 64 ranks, 2 n-tiles).
// x staged fp32->bf16 into LDS; register prefetch keeps global loads in
// flight during the MFMA/ds_read phase. h written as bf16 (2 MB, cached).
__global__ __launch_bounds__(256, 2) void gemm1_kernel(
    const float* __restrict__ x, const __bf16* __restrict__ Abf,
    __bf16* __restrict__ h) {
  __shared__ __bf16 xs[32 * 72];   // 32 rows x 64 k, padded to 72
  __shared__ __bf16 as[64 * 72];   // 64 ranks x 64 k, padded to 72

  const int t = threadIdx.x;
  const int mBase = blockIdx.x * 32;

  // x staging: thread owns row = t>>3, k-offsets c*4 + {0..3, 32..35}
  const int xrow = t >> 3;
  const int xc   = t & 7;
  const float* xg = x + (size_t)(mBase + xrow) * DIN + xc * 4;

  // A staging: thread owns row = t>>2, k-offsets ac*8 + {0..7, 32..39}
  const int arow = t >> 2;
  const int ac   = t & 3;
  const __bf16* ag = Abf + (size_t)arow * DIN + ac * 8;

  const int lane = t & 63;
  const int w    = t >> 6;
  const int mt   = w >> 1;        // 0..1
  const int nh   = w & 1;         // 0..1
  const int lr   = lane & 15;
  const int quad = lane >> 4;

  f32x4 acc0 = {0.f, 0.f, 0.f, 0.f};
  f32x4 acc1 = {0.f, 0.f, 0.f, 0.f};

  // prefetch iteration 0
  float4 f0 = *(const float4*)(xg);
  float4 f1 = *(const float4*)(xg + 32);
  bf16_8 a0 = *(const bf16_8*)(ag);
  bf16_8 a1 = *(const bf16_8*)(ag + 32);

  for (int k0 = 0; k0 < DIN; k0 += 64) {
    __syncthreads();   // previous iteration's LDS reads complete (WAR)

    bf16_4 v;
    v[0] = (__bf16)f0.x; v[1] = (__bf16)f0.y;
    v[2] = (__bf16)f0.z; v[3] = (__bf16)f0.w;
    *(bf16_4*)&xs[xrow * 72 + xc * 4] = v;
    v[0] = (__bf16)f1.x; v[1] = (__bf16)f1.y;
    v[2] = (__bf16)f1.z; v[3] = (__bf16)f1.w;
    *(bf16_4*)&xs[xrow * 72 + xc * 4 + 32] = v;
    *(bf16_8*)&as[arow * 72 + ac * 8] = a0;
    *(bf16_8*)&as[arow * 72 + ac * 8 + 32] = a1;

    __syncthreads();

    if (k0 + 64 < DIN) {  // prefetch next tile; overlaps MFMA phase
      f0 = *(const float4*)(xg + (k0 + 64));
      f1 = *(const float4*)(xg + (k0 + 64) + 32);
      a0 = *(const bf16_8*)(ag + (k0 + 64));
      a1 = *(const bf16_8*)(ag + (k0 + 64) + 32);
    }

#pragma unroll
    for (int ks = 0; ks < 2; ++ks) {
      bf16_8 af  = *(const bf16_8*)&xs[(mt * 16 + lr) * 72 + ks * 32 + quad * 8];
      bf16_8 bf0 = *(const bf16_8*)&as[(nh * 32 + lr) * 72 + ks * 32 + quad * 8];
      bf16_8 bf1 = *(const bf16_8*)&as[(nh * 32 + 16 + lr) * 72 + ks * 32 + quad * 8];
      acc0 = __builtin_amdgcn_mfma_f32_16x16x32_bf16(af, bf0, acc0, 0, 0, 0);
      acc1 = __builtin_amdgcn_mfma_f32_16x16x32_bf16(af, bf1, acc1, 0, 0, 0);
    }
  }

  // epilogue: C/D layout col=lane&15, row=quad*4+i
  const int m = mBase + mt * 16 + quad * 4;
  const int n = nh * 32 + lr;
#pragma unroll
  for (int i = 0; i < 4; ++i) {
    h[(size_t)(m + i) * RANK + n]      = (__bf16)acc0[i];
    h[(size_t)(m + i) * RANK + n + 16] = (__bf16)acc1[i];
  }
}

// ---------------- gemm2: out[M,N] = h[M,64] @ Bbf[N,64]^T ----------------
// BM=BN=128, K=64 staged once. 256 threads (4 waves, 2x2), 64x64 per wave,
// acc = 4x4 fragments. Grid = 32 x 128 = 4096 blocks; write-bound.
__global__ __launch_bounds__(256, 4) void gemm2_kernel(
    const __bf16* __restrict__ h, const __bf16* __restrict__ Bbf,
    float* __restrict__ out) {
  __shared__ __bf16 hs[128 * 72];
  __shared__ __bf16 bs[128 * 72];

  const int t = threadIdx.x;
  const int mBase = blockIdx.y * 128;
  const int nBase = blockIdx.x * 128;

  // stage h tile and B tile (each a contiguous 16 KB chunk of [row][64] bf16)
  {
    const __bf16* hg = h   + (size_t)mBase * RANK;
    const __bf16* bg = Bbf + (size_t)nBase * RANK;
#pragma unroll
    for (int l = 0; l < 4; ++l) {
      int q = l * 2048 + t * 8;        // linear bf16 element index
      bf16_8 hv = *(const bf16_8*)(hg + q);
      bf16_8 bv = *(const bf16_8*)(bg + q);
      int row = q >> 6;
      int col = q & 63;
      *(bf16_8*)&hs[row * 72 + col] = hv;
      *(bf16_8*)&bs[row * 72 + col] = bv;
    }
  }
  __syncthreads();

  const int lane = t & 63;
  const int w    = t >> 6;
  const int wm   = w >> 1;
  const int wn   = w & 1;
  const int lr   = lane & 15;
  const int quad = lane >> 4;

  f32x4 acc[4][4];
#pragma unroll
  for (int mt = 0; mt < 4; ++mt)
#pragma unroll
    for (int nt = 0; nt < 4; ++nt)
      acc[mt][nt] = (f32x4){0.f, 0.f, 0.f, 0.f};

#pragma unroll
  for (int ks = 0; ks < 2; ++ks) {
    bf16_8 af[4], bfr[4];
#pragma unroll
    for (int mt = 0; mt < 4; ++mt)
      af[mt] = *(const bf16_8*)&hs[(wm * 64 + mt * 16 + lr) * 72 + ks * 32 + quad * 8];
#pragma unroll
    for (int nt = 0; nt < 4; ++nt)
      bfr[nt] = *(const bf16_8*)&bs[(wn * 64 + nt * 16 + lr) * 72 + ks * 32 + quad * 8];
#pragma unroll
    for (int mt = 0; mt < 4; ++mt)
#pragma unroll
      for (int nt = 0; nt < 4; ++nt)
        acc[mt][nt] = __builtin_amdgcn_mfma_f32_16x16x32_bf16(af[mt], bfr[nt], acc[mt][nt], 0, 0, 0);
  }

  // epilogue: scaling already folded into Bbf
#pragma unroll
  for (int mt = 0; mt < 4; ++mt) {
    int m = mBase + wm * 64 + mt * 16 + quad * 4;
#pragma unroll
    for (int nt = 0; nt < 4; ++nt) {
      int n = nBase + wn * 64 + nt * 16 + lr;
#pragma unroll
      for (int i = 0; i < 4; ++i)
        out[(size_t)(m + i) * DOUT + n] = acc[mt][nt][i];
    }
  }
}

extern "C" void kernel_launch(void* const* d_in, const int* in_sizes, int n_in,
                              void* d_out, int out_size, void* d_ws, size_t ws_size,
                              hipStream_t stream) {
  const float* x  = (const float*)d_in[0];
  const float* A  = (const float*)d_in[1];
  const float* Bm = (const float*)d_in[2];
  const float* sA = (const float*)d_in[3];
  const float* sB = (const float*)d_in[4];
  float* out = (float*)d_out;

  // workspace layout: Abf (512 KB) | Bbf (512 KB) | h (2 MB)  => 3 MB
  __bf16* Abf = (__bf16*)d_ws;
  __bf16* Bbf = Abf + (size_t)RANK * DIN;
  __bf16* h   = Bbf + (size_t)DOUT * RANK;

  prep_kernel<<<256, 256, 0, stream>>>(A, Bm, sA, sB, Abf, Bbf);
  gemm1_kernel<<<M_TOTAL / 32, 256, 0, stream>>>(x, Abf, h);
  gemm2_kernel<<<dim3(DOUT / 128, M_TOTAL / 128), 256, 0, stream>>>(h, Bbf, out);
}